// Round 2
// baseline (411.086 us; speedup 1.0000x reference)
//
#include <hip/hip_runtime.h>
#include <math.h>

#define BATCH 8
#define CIN 128
#define OCH 128
#define HH 64
#define WW 64
#define HW (HH*WW)
#define NPIX (BATCH*HW)

// ---- workspace layout (float element offsets) ----
#define XT_OFF  0
#define XT_SZ   (BATCH*HW*CIN)            // 4,194,304  x transposed to NHWC
#define WT_OFF  (XT_OFF + XT_SZ)
#define WT_SZ   (9*CIN*OCH)               // 147,456    conv_w as [k][c][o]
#define WOM_OFF (WT_OFF + WT_SZ)
#define WOM_SZ  (9*CIN*28)                // 32,256     off/mask weights [k][c][28]
#define PMM_OFF (WOM_OFF + WOM_SZ)
#define PMM_SZ  (NPIX*32)                 // 1,048,576  per-pixel py[9],px[9],m[9]
// total ws: ~21.7 MB

// ============ kernel 1a: x NCHW -> NHWC ============
__global__ __launch_bounds__(256) void k_transpose_x(const float* __restrict__ x,
                                                     float* __restrict__ xt) {
    __shared__ float tile[32][33];
    int b   = blockIdx.z;
    int hw0 = blockIdx.x * 32;
    int c0  = blockIdx.y * 32;
    int tx = threadIdx.x, ty = threadIdx.y;
    const float* xin = x  + (size_t)b*CIN*HW;
    float*       xo  = xt + (size_t)b*HW*CIN;
    #pragma unroll
    for (int r = 0; r < 32; r += 8)
        tile[ty + r][tx] = xin[(size_t)(c0 + ty + r)*HW + hw0 + tx];
    __syncthreads();
    #pragma unroll
    for (int r = 0; r < 32; r += 8)
        xo[(size_t)(hw0 + ty + r)*CIN + c0 + tx] = tile[tx][ty + r];
}

// ============ kernel 1b: pack weights ============
// wt[k][c][o] = conv_w[o][c][k]   (k = ky*3+kx)
// wom[k][c][j] (j<18: off_w[j][c][k], 18<=j<27: mask_w[j-18][c][k], j=27 pad)
__global__ __launch_bounds__(256) void k_pack_w(const float* __restrict__ conv_w,
                                                const float* __restrict__ off_w,
                                                const float* __restrict__ mask_w,
                                                float* __restrict__ wt,
                                                float* __restrict__ wom) {
    int idx = blockIdx.x * 256 + threadIdx.x;
    if (idx < 9*CIN*OCH) {
        int k = idx / (CIN*OCH);
        int rc = idx - k*(CIN*OCH);
        int c = rc / OCH;
        int o = rc - c*OCH;
        wt[idx] = conv_w[(size_t)(o*CIN + c)*9 + k];
    }
    if (idx < 9*CIN*28) {
        int k = idx / (CIN*28);
        int r2 = idx - k*(CIN*28);
        int c = r2 / 28;
        int j = r2 - c*28;
        float v = 0.f;
        if (j < 18)      v = off_w [(size_t)(j*CIN + c)*9 + k];
        else if (j < 27) v = mask_w[(size_t)((j-18)*CIN + c)*9 + k];
        wom[idx] = v;
    }
}

// ============ kernel 2: offset+mask conv -> pmm ============
// block = 256 threads = 64 pixels (one (b,h) row) x 4 c-groups; grid = B*H = 512
__global__ __launch_bounds__(256) void k_offmask(const float* __restrict__ x,
                                                 const float* __restrict__ wom,
                                                 const float* __restrict__ off_b,
                                                 const float* __restrict__ mask_b,
                                                 float* __restrict__ pmm) {
    int b = blockIdx.x >> 6;
    int h = blockIdx.x & 63;
    int t = threadIdx.x;
    int p = t & 63;                                    // pixel (abs w)
    int cg = __builtin_amdgcn_readfirstlane(t >> 6);   // wave-uniform c-group

    float acc[27];
    #pragma unroll
    for (int j = 0; j < 27; ++j) acc[j] = 0.f;

    const float* xb = x + (size_t)b*CIN*HW;
    for (int k = 0; k < 9; ++k) {
        int ky = k / 3, kx = k - ky*3;
        int y = h + ky - 1;
        if ((unsigned)y >= HH) continue;
        int xx = p + kx - 1;
        bool vx = (unsigned)xx < WW;
        const float* xp = xb + (size_t)(cg*32)*HW + y*WW + xx;
        const float* wp = wom + (size_t)(k*CIN + cg*32)*28;   // uniform -> s_load
        #pragma unroll
        for (int i = 0; i < 32; ++i) {
            float xv = vx ? xp[(size_t)i*HW] : 0.f;
            #pragma unroll
            for (int j = 0; j < 27; ++j)
                acc[j] = fmaf(xv, wp[i*28 + j], acc[j]);
        }
    }

    __shared__ float red[4][64][29];
    #pragma unroll
    for (int j = 0; j < 27; ++j) red[cg][p][j] = acc[j];
    __syncthreads();

    int jq = t >> 6;                  // 0..3 -> j-ranges 0-6,7-13,14-20,21-26
    int pix = (b*HH + h)*WW + p;
    int nj = (jq == 3) ? 6 : 7;
    for (int u = 0; u < nj; ++u) {
        int j = jq*7 + u;
        float s = red[0][p][j] + red[1][p][j] + red[2][p][j] + red[3][p][j];
        float outv; int slot;
        if (j < 18) {
            int kk = j >> 1;
            s += off_b[j];
            int kyy = kk / 3;
            if ((j & 1) == 0) { outv = (float)(h - 1 + kyy) + s;            slot = kk;     }
            else              { outv = (float)(p - 1 + (kk - kyy*3)) + s;   slot = 9 + kk; }
        } else {
            s += mask_b[j - 18];
            outv = 1.f / (1.f + expf(-s));
            slot = j;                 // 18..26
        }
        pmm[(size_t)pix*32 + slot] = outv;
    }
}

// ============ kernel 3: gather + main GEMM ============
// block = 128 threads (2 waves), 32 pixels (half row). grid = B*H*2 = 1024
// (= exactly 4 blocks/CU, no tail).
// per k: stage cols[c][p] (mask applied) in LDS, then register-tiled GEMM:
// thread tile 8 o x 4 p, og = t>>3 (0..15, o=og*8), pg = t&7 (p=pg*4).
// Weights stay on the global/L1 path (8-way lane-duplicate reads broadcast);
// LDS-staging them was rejected on paper: +2 ds_read_b128/c/thread would blow
// the per-CU LDS budget (~24 wave-b128/c ~ 220-290 cyc) past the 128-cyc VALU
// wall -> LDS-bound regression.
__global__ __launch_bounds__(128) void k_main(const float* __restrict__ xt,
                                              const float* __restrict__ wt,
                                              const float* __restrict__ pmm,
                                              float* __restrict__ out) {
    __shared__ float cols[CIN][32];
    __shared__ float spy[9][32], spx[9][32], spm[9][32];

    int blk = blockIdx.x;
    int b = blk >> 7;
    int r = blk & 127;
    int h = r >> 1;
    int w0 = (r & 1) << 5;
    int t = threadIdx.x;

    // stage per-pixel positions/mask
    int rowpix = (b*HH + h)*WW + w0;
    for (int idx = t; idx < 32*32; idx += 128) {
        int p = idx >> 5, s = idx & 31;
        float v = pmm[(size_t)(rowpix + p)*32 + s];
        if (s < 9)       spy[s][p]      = v;
        else if (s < 18) spx[s - 9][p]  = v;
        else if (s < 27) spm[s - 18][p] = v;
    }

    float acc[8][4];
    #pragma unroll
    for (int i = 0; i < 8; ++i)
        #pragma unroll
        for (int j = 0; j < 4; ++j) acc[i][j] = 0.f;

    int og = t >> 3, pg = t & 7;      // GEMM roles
    int gp = t >> 2, cq = t & 3;      // gather roles: pixel, c-quarter
    const float* xb = xt + (size_t)b*HW*CIN;

    for (int k = 0; k < 9; ++k) {
        __syncthreads();              // prior GEMM done reading cols / staging done

        // ---- gather: 4 bilinear taps for (pixel gp, channels cq*32..+31) ----
        float py = spy[k][gp], px = spx[k][gp], m = spm[k][gp];
        float fy = floorf(py), fx = floorf(px);
        float wy = py - fy, wx = px - fx;
        int iy = (int)fy, ix = (int)fx;

        float a[32];
        #pragma unroll
        for (int i = 0; i < 32; ++i) a[i] = 0.f;

        int   tys[4] = { iy, iy, iy + 1, iy + 1 };
        int   txs[4] = { ix, ix + 1, ix, ix + 1 };
        float tws[4] = { (1.f-wy)*(1.f-wx), (1.f-wy)*wx, wy*(1.f-wx), wy*wx };
        #pragma unroll
        for (int tp = 0; tp < 4; ++tp) {
            int yy = tys[tp], xxv = txs[tp];
            if ((unsigned)yy < HH && (unsigned)xxv < WW) {
                const float* src = xb + ((size_t)yy*WW + xxv)*CIN + cq*32;
                float tw = tws[tp];
                #pragma unroll
                for (int i = 0; i < 8; ++i) {
                    float4 v = *(const float4*)(src + i*4);
                    a[4*i+0] = fmaf(tw, v.x, a[4*i+0]);
                    a[4*i+1] = fmaf(tw, v.y, a[4*i+1]);
                    a[4*i+2] = fmaf(tw, v.z, a[4*i+2]);
                    a[4*i+3] = fmaf(tw, v.w, a[4*i+3]);
                }
            }
        }
        #pragma unroll
        for (int i = 0; i < 32; ++i) cols[cq*32 + i][gp] = m * a[i];

        __syncthreads();              // cols ready

        // ---- GEMM: acc[o][p] += wt[k][c][o] * cols[c][p] ----
        const float* wk = wt + (size_t)k*CIN*OCH;
        #pragma unroll 4
        for (int c = 0; c < CIN; ++c) {
            const float* wr = wk + c*OCH + og*8;
            float4 wv0 = *(const float4*)(wr);
            float4 wv1 = *(const float4*)(wr + 4);
            float4 cv  = *(const float4*)(&cols[c][pg*4]);
            float wsv[8] = { wv0.x, wv0.y, wv0.z, wv0.w, wv1.x, wv1.y, wv1.z, wv1.w };
            float csv[4] = { cv.x, cv.y, cv.z, cv.w };
            #pragma unroll
            for (int i = 0; i < 8; ++i)
                #pragma unroll
                for (int j = 0; j < 4; ++j)
                    acc[i][j] = fmaf(wsv[i], csv[j], acc[i][j]);
        }
    }

    // ---- store NCHW ----
    float* ob = out + (size_t)b*OCH*HW + h*WW + w0 + pg*4;
    #pragma unroll
    for (int i = 0; i < 8; ++i) {
        int o = og*8 + i;
        *(float4*)(ob + (size_t)o*HW) = make_float4(acc[i][0], acc[i][1], acc[i][2], acc[i][3]);
    }
}

extern "C" void kernel_launch(void* const* d_in, const int* in_sizes, int n_in,
                              void* d_out, int out_size, void* d_ws, size_t ws_size,
                              hipStream_t stream) {
    const float* x      = (const float*)d_in[0];
    const float* conv_w = (const float*)d_in[1];
    const float* off_w  = (const float*)d_in[2];
    const float* off_b  = (const float*)d_in[3];
    const float* mask_w = (const float*)d_in[4];
    const float* mask_b = (const float*)d_in[5];
    float* out = (float*)d_out;
    float* ws  = (float*)d_ws;

    float* xt  = ws + XT_OFF;
    float* wtp = ws + WT_OFF;
    float* wom = ws + WOM_OFF;
    float* pmm = ws + PMM_OFF;

    k_transpose_x<<<dim3(128, 4, 8), dim3(32, 8), 0, stream>>>(x, xt);
    k_pack_w<<<576, 256, 0, stream>>>(conv_w, off_w, mask_w, wtp, wom);
    k_offmask<<<512, 256, 0, stream>>>(x, wom, off_b, mask_b, pmm);
    k_main<<<1024, 128, 0, stream>>>(xt, wtp, pmm, out);
}

// Round 3
// 332.754 us; speedup vs baseline: 1.2354x; 1.2354x over previous
//
#include <hip/hip_runtime.h>
#include <math.h>

#define BATCH 8
#define CIN 128
#define OCH 128
#define HH 64
#define WW 64
#define HW (HH*WW)
#define NPIX (BATCH*HW)

// ---- workspace layout (float element offsets) ----
#define XT_OFF  0
#define XT_SZ   (BATCH*HW*CIN)            // x transposed to NHWC
#define WT_OFF  (XT_OFF + XT_SZ)
#define WT_SZ   (9*CIN*OCH)               // conv_w as [k][c][o]
#define WOM_OFF (WT_OFF + WT_SZ)
#define WOM_SZ  (9*CIN*28)                // off/mask weights [k][c][28]
#define PMM_OFF (WOM_OFF + WOM_SZ)
#define PMM_SZ  (NPIX*32)                 // per-pixel py[9],px[9],m[9]

// ============ kernel 1a: x NCHW -> NHWC ============
__global__ __launch_bounds__(256) void k_transpose_x(const float* __restrict__ x,
                                                     float* __restrict__ xt) {
    __shared__ float tile[32][33];
    int b   = blockIdx.z;
    int hw0 = blockIdx.x * 32;
    int c0  = blockIdx.y * 32;
    int tx = threadIdx.x, ty = threadIdx.y;
    const float* xin = x  + (size_t)b*CIN*HW;
    float*       xo  = xt + (size_t)b*HW*CIN;
    #pragma unroll
    for (int r = 0; r < 32; r += 8)
        tile[ty + r][tx] = xin[(size_t)(c0 + ty + r)*HW + hw0 + tx];
    __syncthreads();
    #pragma unroll
    for (int r = 0; r < 32; r += 8)
        xo[(size_t)(hw0 + ty + r)*CIN + c0 + tx] = tile[tx][ty + r];
}

// ============ kernel 1b: pack weights ============
__global__ __launch_bounds__(256) void k_pack_w(const float* __restrict__ conv_w,
                                                const float* __restrict__ off_w,
                                                const float* __restrict__ mask_w,
                                                float* __restrict__ wt,
                                                float* __restrict__ wom) {
    int idx = blockIdx.x * 256 + threadIdx.x;
    if (idx < 9*CIN*OCH) {
        int k = idx / (CIN*OCH);
        int rc = idx - k*(CIN*OCH);
        int c = rc / OCH;
        int o = rc - c*OCH;
        wt[idx] = conv_w[(size_t)(o*CIN + c)*9 + k];
    }
    if (idx < 9*CIN*28) {
        int k = idx / (CIN*28);
        int r2 = idx - k*(CIN*28);
        int c = r2 / 28;
        int j = r2 - c*28;
        float v = 0.f;
        if (j < 18)      v = off_w [(size_t)(j*CIN + c)*9 + k];
        else if (j < 27) v = mask_w[(size_t)((j-18)*CIN + c)*9 + k];
        wom[idx] = v;
    }
}

// ============ kernel 2: offset+mask conv -> pmm ============
// block = 512 threads = 64 px (full row) x 8 c-groups of 16ch (wave-uniform cg)
// grid = B*H = 512  ->  4096 waves = 16 waves/CU (was 8)
__global__ __launch_bounds__(512) void k_offmask(const float* __restrict__ x,
                                                 const float* __restrict__ wom,
                                                 const float* __restrict__ off_b,
                                                 const float* __restrict__ mask_b,
                                                 float* __restrict__ pmm) {
    int b = blockIdx.x >> 6;
    int h = blockIdx.x & 63;
    int t = threadIdx.x;
    int p = t & 63;                                    // pixel (abs w)
    int cg = __builtin_amdgcn_readfirstlane(t >> 6);   // 0..7, wave-uniform

    float acc[27];
    #pragma unroll
    for (int j = 0; j < 27; ++j) acc[j] = 0.f;

    const float* xb = x + (size_t)b*CIN*HW + (size_t)(cg*16)*HW;
    const float* wbase = wom + (size_t)(cg*16)*28;
    for (int k = 0; k < 9; ++k) {
        int ky = k / 3, kx = k - ky*3;
        int y = h + ky - 1;
        if ((unsigned)y >= HH) continue;
        int xx = p + kx - 1;
        bool vx = (unsigned)xx < WW;
        const float* xp = xb + y*WW + xx;
        const float* wp = wbase + (size_t)k*CIN*28;    // wave-uniform -> s_load
        #pragma unroll
        for (int i = 0; i < 16; ++i) {
            float xv = vx ? xp[(size_t)i*HW] : 0.f;
            #pragma unroll
            for (int j = 0; j < 27; ++j)
                acc[j] = fmaf(xv, wp[i*28 + j], acc[j]);
        }
    }

    __shared__ float red[8][64][33];                   // +1 pad: 2-way banks
    #pragma unroll
    for (int j = 0; j < 27; ++j) red[cg][p][j] = acc[j];
    __syncthreads();

    int rowpix = (b*HH + h)*WW;
    for (int idx = t; idx < 64*32; idx += 512) {
        int pp = idx >> 5, j = idx & 31;
        if (j >= 27) continue;
        float s = 0.f;
        #pragma unroll
        for (int g = 0; g < 8; ++g) s += red[g][pp][j];
        float outv; int slot;
        if (j < 18) {
            int kk = j >> 1;
            s += off_b[j];
            int kyy = kk / 3;
            if ((j & 1) == 0) { outv = (float)(h - 1 + kyy) + s;            slot = kk;     }
            else              { outv = (float)(pp - 1 + (kk - kyy*3)) + s;  slot = 9 + kk; }
        } else {
            s += mask_b[j - 18];
            outv = 1.f / (1.f + expf(-s));
            slot = j;
        }
        pmm[(size_t)(rowpix + pp)*32 + slot] = outv;
    }
}

// ============ kernel 3: gather + main GEMM ============
// block = 256 threads (4 waves), 32 px. grid = 1024 = exactly 4 blocks/CU
// -> 16 waves/CU (was 8). Thread tile 4o x 4p (og=t>>3 0..31, pg=t&7).
// cols double-buffered + XOR-swizzled: element (c,p) lives at dword
//   c*32 + (((p>>2) ^ (c>>4))<<2) + (p&3)
// writes (scalar, per gather thread: 16 c's for one p): 2-way banks = free.
// reads (float4, wave-uniform c): 8 distinct 16B blocks spanning all 32 banks.
__global__ __launch_bounds__(256, 4) void k_main(const float* __restrict__ xt,
                                                 const float* __restrict__ wt,
                                                 const float* __restrict__ pmm,
                                                 float* __restrict__ out) {
    __shared__ float cols[2][CIN*32];                  // 32 KB

    int blk = blockIdx.x;
    int b = blk >> 7;
    int r = blk & 127;
    int h = r >> 1;
    int w0 = (r & 1) << 5;
    int t = threadIdx.x;

    int og = t >> 3, pg = t & 7;      // GEMM roles
    int gpx = t >> 3, gcg = t & 7;    // gather roles: pixel, 16-ch group

    int rowpix = (b*HH + h)*WW + w0;
    const float* xb = xt + (size_t)b*HW*CIN;
    const float* pmmp = pmm + (size_t)(rowpix + gpx)*32;

    // swizzled write base (dwords), c = gcg*16 + i
    int wbase = gcg*16*32 + (((gpx >> 2) ^ gcg) << 2) + (gpx & 3);

    float acc[4][4];
    #pragma unroll
    for (int i = 0; i < 4; ++i)
        #pragma unroll
        for (int j = 0; j < 4; ++j) acc[i][j] = 0.f;

    auto gather = [&](int kk, int buf) {
        float py = pmmp[kk];
        float qx = pmmp[9 + kk];
        float m  = pmmp[18 + kk];
        float fy = floorf(py), fx = floorf(qx);
        float wy = py - fy, wx = qx - fx;
        int iy = (int)fy, ix = (int)fx;
        float a[16];
        #pragma unroll
        for (int i = 0; i < 16; ++i) a[i] = 0.f;
        int   tys[4] = { iy, iy, iy + 1, iy + 1 };
        int   txs[4] = { ix, ix + 1, ix, ix + 1 };
        float tws[4] = { (1.f-wy)*(1.f-wx), (1.f-wy)*wx, wy*(1.f-wx), wy*wx };
        #pragma unroll
        for (int tp = 0; tp < 4; ++tp) {
            int yy = tys[tp], xv = txs[tp];
            if ((unsigned)yy < HH && (unsigned)xv < WW) {
                const float* src = xb + (size_t)(yy*WW + xv)*CIN + gcg*16;
                float tw = tws[tp];
                #pragma unroll
                for (int q = 0; q < 4; ++q) {
                    float4 v = *(const float4*)(src + q*4);
                    a[4*q+0] = fmaf(tw, v.x, a[4*q+0]);
                    a[4*q+1] = fmaf(tw, v.y, a[4*q+1]);
                    a[4*q+2] = fmaf(tw, v.z, a[4*q+2]);
                    a[4*q+3] = fmaf(tw, v.w, a[4*q+3]);
                }
            }
        }
        float* cb = &cols[buf][0] + wbase;
        #pragma unroll
        for (int i = 0; i < 16; ++i) cb[i*32] = m * a[i];
    };

    auto gemm = [&](int kk, int buf) {
        const float* wk = wt + (size_t)kk*CIN*OCH + og*4;
        const float* cb = &cols[buf][0];
        for (int g = 0; g < 8; ++g) {                  // c = g*16 + i
            const float* cbg = cb + g*16*32 + ((pg ^ g) << 2);
            const float* wkg = wk + (size_t)g*16*OCH;
            #pragma unroll
            for (int i = 0; i < 16; ++i) {
                float4 wv = *(const float4*)(wkg + (size_t)i*OCH);
                float4 cv = *(const float4*)(cbg + i*32);
                acc[0][0] = fmaf(wv.x, cv.x, acc[0][0]);
                acc[0][1] = fmaf(wv.x, cv.y, acc[0][1]);
                acc[0][2] = fmaf(wv.x, cv.z, acc[0][2]);
                acc[0][3] = fmaf(wv.x, cv.w, acc[0][3]);
                acc[1][0] = fmaf(wv.y, cv.x, acc[1][0]);
                acc[1][1] = fmaf(wv.y, cv.y, acc[1][1]);
                acc[1][2] = fmaf(wv.y, cv.z, acc[1][2]);
                acc[1][3] = fmaf(wv.y, cv.w, acc[1][3]);
                acc[2][0] = fmaf(wv.z, cv.x, acc[2][0]);
                acc[2][1] = fmaf(wv.z, cv.y, acc[2][1]);
                acc[2][2] = fmaf(wv.z, cv.z, acc[2][2]);
                acc[2][3] = fmaf(wv.z, cv.w, acc[2][3]);
                acc[3][0] = fmaf(wv.w, cv.x, acc[3][0]);
                acc[3][1] = fmaf(wv.w, cv.y, acc[3][1]);
                acc[3][2] = fmaf(wv.w, cv.z, acc[3][2]);
                acc[3][3] = fmaf(wv.w, cv.w, acc[3][3]);
            }
        }
    };

    gather(0, 0);
    __syncthreads();
    for (int k = 0; k < 9; ++k) {
        int buf = k & 1;
        gemm(k, buf);
        if (k < 8) gather(k + 1, buf ^ 1);   // writes other buffer: no race
        __syncthreads();
    }

    // ---- store NCHW ----
    float* ob = out + (size_t)b*OCH*HW + (size_t)h*WW + w0 + pg*4;
    #pragma unroll
    for (int i = 0; i < 4; ++i) {
        int o = og*4 + i;
        *(float4*)(ob + (size_t)o*HW) = make_float4(acc[i][0], acc[i][1], acc[i][2], acc[i][3]);
    }
}

extern "C" void kernel_launch(void* const* d_in, const int* in_sizes, int n_in,
                              void* d_out, int out_size, void* d_ws, size_t ws_size,
                              hipStream_t stream) {
    const float* x      = (const float*)d_in[0];
    const float* conv_w = (const float*)d_in[1];
    const float* off_w  = (const float*)d_in[2];
    const float* off_b  = (const float*)d_in[3];
    const float* mask_w = (const float*)d_in[4];
    const float* mask_b = (const float*)d_in[5];
    float* out = (float*)d_out;
    float* ws  = (float*)d_ws;

    float* xt  = ws + XT_OFF;
    float* wtp = ws + WT_OFF;
    float* wom = ws + WOM_OFF;
    float* pmm = ws + PMM_OFF;

    k_transpose_x<<<dim3(128, 4, 8), dim3(32, 8), 0, stream>>>(x, xt);
    k_pack_w<<<576, 256, 0, stream>>>(conv_w, off_w, mask_w, wtp, wom);
    k_offmask<<<512, 512, 0, stream>>>(x, wom, off_b, mask_b, pmm);
    k_main<<<1024, 256, 0, stream>>>(xt, wtp, pmm, out);
}